// Round 19
// baseline (1637.091 us; speedup 1.0000x reference)
//
#include <hip/hip_runtime.h>
#include <math.h>

#define DMODEL 768
#define NHEAD 12
#define DHEAD 64
#define HIDDEN 3072
#define NLAYER 6
#define SEQ 1024
#define AC_ELEMS (SEQ * DMODEL)

typedef unsigned short u16;
typedef __attribute__((ext_vector_type(8))) short short8;
typedef __attribute__((ext_vector_type(4))) float f32x4;
typedef __attribute__((ext_vector_type(4))) unsigned short u16x4;

__device__ __forceinline__ u16 f2bf(float f) {
    union { float f; unsigned u; } v; v.f = f;
    unsigned u = v.u;
    return (u16)((u + 0x7fffu + ((u >> 16) & 1u)) >> 16);
}
__device__ __forceinline__ float bf2f(u16 b) {
    union { unsigned u; float f; } v; v.u = ((unsigned)b) << 16; return v.f;
}

// async global->LDS, 16B/lane; LDS base wave-uniform (HW adds lane*16)
__device__ __forceinline__ void async16(const void* g, void* l) {
    __builtin_amdgcn_global_load_lds(
        (const __attribute__((address_space(1))) unsigned int*)g,
        (__attribute__((address_space(3))) unsigned int*)l, 16, 0, 0);
}

// counted vmcnt wait + scheduling fence (rule #18)
template<int N> __device__ __forceinline__ void waitv() {
    asm volatile("s_waitcnt vmcnt(%0)" :: "n"(N) : "memory");
    __builtin_amdgcn_sched_barrier(0);
}
__device__ __forceinline__ void drain_all() {
    asm volatile("s_waitcnt vmcnt(0) lgkmcnt(0)" ::: "memory");
    __builtin_amdgcn_sched_barrier(0);
}
__device__ __forceinline__ void bar() {
    __builtin_amdgcn_sched_barrier(0);
    __builtin_amdgcn_s_barrier();
    __builtin_amdgcn_sched_barrier(0);
}

// ---------------------------------------------------------------- reductions
__device__ __forceinline__ float block_sum(float v, float* red) {
    int tid = threadIdx.x;
    red[tid] = v;
    __syncthreads();
#pragma unroll
    for (int s = 128; s > 0; s >>= 1) {
        if (tid < s) red[tid] += red[tid + s];
        __syncthreads();
    }
    float r = red[0];
    __syncthreads();
    return r;
}
__device__ __forceinline__ float block_max(float v, float* red) {
    int tid = threadIdx.x;
    red[tid] = v;
    __syncthreads();
#pragma unroll
    for (int s = 128; s > 0; s >>= 1) {
        if (tid < s) red[tid] = fmaxf(red[tid], red[tid + s]);
        __syncthreads();
    }
    float r = red[0];
    __syncthreads();
    return r;
}

// ---------------------------------------------------------------- small kernels
__global__ __launch_bounds__(256) void add_pe2(const float* __restrict__ a0,
                                               const float* __restrict__ a1,
                                               const float* __restrict__ pe,
                                               float* __restrict__ o0,
                                               float* __restrict__ o1,
                                               u16* __restrict__ ob0,
                                               u16* __restrict__ ob1, int n) {
    int i = blockIdx.x * 256 + threadIdx.x;
    if (i >= n) return;
    const float* a = blockIdx.y ? a1 : a0;
    float* o = blockIdx.y ? o1 : o0;
    u16* ob = blockIdx.y ? ob1 : ob0;
    float v = a[i] + pe[i];
    o[i] = v; ob[i] = f2bf(v);
}

// one-launch weight conversion: 16 segments, 4096 f32/block, 32-bit index math.
// Nontemporal loads AND stores: src read-once; W (297MB) exceeds L3 anyway.
struct CvtSeg { const float* src; long long dst; int bpl; long long sls; long long dls; };
struct CvtDesc { CvtSeg seg[16]; int blkStart[17]; };

__global__ __launch_bounds__(256) void cvt_all(CvtDesc d, u16* __restrict__ W) {
    int b = blockIdx.x, s = 0;
#pragma unroll 1
    while (b >= d.blkStart[s + 1]) ++s;
    const CvtSeg g = d.seg[s];
    int rel = b - d.blkStart[s];
    int layer = rel / g.bpl;
    int blkInL = rel - layer * g.bpl;
    const float* src = g.src + (long long)layer * g.sls + (long long)blkInL * 4096;
    u16* dst = W + g.dst + (long long)layer * g.dls + (long long)blkInL * 4096;
#pragma unroll
    for (int j = 0; j < 4; ++j) {
        int idx = (j * 256 + threadIdx.x) * 4;
        f32x4 v = __builtin_nontemporal_load((const f32x4*)(src + idx));
        u16x4 o;
        o.x = f2bf(v.x); o.y = f2bf(v.y); o.z = f2bf(v.z); o.w = f2bf(v.w);
        __builtin_nontemporal_store(o, (u16x4*)(dst + idx));
    }
}

// ---------------------------------------------------------------- MFMA GEMM
// DB-buffer (3 when LDS fits, else 2), counted vmcnt (pure-bf16 path).
// C[N x M] = A[N x K](bf16) * B[M x K]^T (+bias) (+relu)
// B: bf16 (async) or f32 (reg-staged convert).
// blockIdx.z = K-split; z>0 writes f32 partial to C2 + (z-1)*AC.
// vt_mode: 0 none; 1 cols>=vt_col0 transposed to vt_out; 2 periodic k|v (1536):
//          rem=col%1536>=768 -> vt_out[((col/1536)*768+rem-768)*SEQ+row].
template<int TM, int TN, int WR, int WC>
__global__ __launch_bounds__(WR * WC * 64) void gemm_mfma(
    const u16* __restrict__ A, int lda,
    const void* __restrict__ Bp, int ldb, int b_f32,
    const float* __restrict__ bias,
    void* __restrict__ Cp, int ldc, int c_bf16,
    float* __restrict__ C2,
    u16* __restrict__ vt_out, int vt_col0, int vt_mode,
    int Ksub, int relu)
{
    constexpr int T  = WR * WC * 64;
    constexpr bool MW = (WR * WC) > 1;
    constexpr int FM = TM / (WR * 16), FN = TN / (WC * 16);
    constexpr int NA = TM * 8 / T, NB = TN * 8 / T;
    constexpr int LPS = NA + NB;
    constexpr int DB = (3 * (TM + TN) * 64 * 2 <= 65536) ? 3 : 2;
    constexpr int DEPTH = DB - 1;
    __shared__ __align__(16) u16 As[DB][TM * 64];
    __shared__ __align__(16) u16 Bs[DB][TN * 64];

    const int zs = blockIdx.z;
    const u16*   B16 = (const u16*)Bp   + (long long)zs * Ksub;
    const float* B32 = (const float*)Bp + (long long)zs * Ksub;
    A += (long long)zs * Ksub;
    u16*   C16 = (u16*)Cp;
    float* C32 = (float*)Cp;

    const int t = threadIdx.x, lane = t & 63, w = t >> 6;
    const int wy = w / WC, wx = w % WC;
    const int n0 = blockIdx.y * TM, m0 = blockIdx.x * TN;

    auto stage = [&](int b, int k0) {
#pragma unroll
        for (int i = 0; i < NA; ++i) {
            int L = i * T + t;
            int row = L >> 3, cp = L & 7, c = cp ^ (row & 7);
            async16(A + (long long)(n0 + row) * lda + k0 + (c << 3),
                    &As[b][(i * T + w * 64) * 8]);
        }
        if (!b_f32) {
#pragma unroll
            for (int i = 0; i < NB; ++i) {
                int L = i * T + t;
                int row = L >> 3, cp = L & 7, c = cp ^ (row & 7);
                async16(B16 + (long long)(m0 + row) * ldb + k0 + (c << 3),
                        &Bs[b][(i * T + w * 64) * 8]);
            }
        } else {
#pragma unroll
            for (int i = 0; i < NB; ++i) {
                int L = i * T + t;
                int row = L >> 3, cp = L & 7, c = cp ^ (row & 7);
                const float* s = B32 + (long long)(m0 + row) * ldb + k0 + (c << 3);
                float4 x = *(const float4*)s;
                float4 y = *(const float4*)(s + 4);
                uint4 pk;
                pk.x = (unsigned)f2bf(x.x) | ((unsigned)f2bf(x.y) << 16);
                pk.y = (unsigned)f2bf(x.z) | ((unsigned)f2bf(x.w) << 16);
                pk.z = (unsigned)f2bf(y.x) | ((unsigned)f2bf(y.y) << 16);
                pk.w = (unsigned)f2bf(y.z) | ((unsigned)f2bf(y.w) << 16);
                *(uint4*)&Bs[b][row * 64 + cp * 8] = pk;
            }
        }
    };

    const int nk = Ksub / 64;
    stage(0, 0);
    if (DEPTH > 1 && nk > 1) stage(1, 64);

    f32x4 acc[FM][FN] = {};

    for (int tt = 0; tt < nk; ++tt) {
        if (tt + DEPTH < nk) stage((tt + DEPTH) % DB, (tt + DEPTH) * 64);
        if (b_f32) drain_all();
        else {
            int inflight = nk - 1 - tt;
            if (inflight > DEPTH) inflight = DEPTH;
            if (DEPTH == 2) {
                if (inflight == 2)      waitv<2 * LPS>();
                else if (inflight == 1) waitv<LPS>();
                else                    waitv<0>();
            } else {
                if (inflight >= 1) waitv<LPS>();
                else               waitv<0>();
            }
        }
        if (MW) bar();

        const u16* Ac = As[tt % DB];
        const u16* Bc = Bs[tt % DB];
#pragma unroll
        for (int kk = 0; kk < 2; ++kk) {
            short8 af[FM], bfv[FN];
            const int cb = kk * 4 + (lane >> 4);
#pragma unroll
            for (int m = 0; m < FM; ++m) {
                int R = wy * (TM / WR) + m * 16 + (lane & 15);
                af[m] = *(const short8*)&Ac[R * 64 + ((cb ^ (R & 7)) << 3)];
            }
#pragma unroll
            for (int n = 0; n < FN; ++n) {
                int R = wx * (TN / WC) + n * 16 + (lane & 15);
                bfv[n] = *(const short8*)&Bc[R * 64 + ((cb ^ (R & 7)) << 3)];
            }
#pragma unroll
            for (int m = 0; m < FM; ++m)
#pragma unroll
                for (int n = 0; n < FN; ++n)
                    acc[m][n] = __builtin_amdgcn_mfma_f32_16x16x32_bf16(af[m], bfv[n], acc[m][n], 0, 0, 0);
        }
        if (MW) bar();
    }

    const int cj = lane & 15, ci0 = (lane >> 4) << 2;
    const bool z0 = (zs == 0);
    float* C2z = C2 + (long long)(zs - 1) * AC_ELEMS;
#pragma unroll
    for (int m = 0; m < FM; ++m) {
#pragma unroll
        for (int n = 0; n < FN; ++n) {
            int col = m0 + wx * (TN / WC) + n * 16 + cj;
            float bv = (z0 && bias) ? bias[col] : 0.0f;
            long long vtidx = -1;
            if (z0 && vt_mode == 1 && col >= vt_col0) vtidx = (long long)(col - vt_col0) * SEQ;
            else if (z0 && vt_mode == 2) {
                int blk = col / 1536, rem = col % 1536;
                if (rem >= 768) vtidx = ((long long)blk * 768 + rem - 768) * SEQ;
            }
#pragma unroll
            for (int r = 0; r < 4; ++r) {
                int row = n0 + wy * (TM / WR) + m * 16 + ci0 + r;
                float v = acc[m][n][r] + bv;
                if (relu) v = fmaxf(v, 0.0f);
                if (!z0)             C2z[(long long)row * ldc + col] = v;
                else if (vtidx >= 0) vt_out[vtidx + row] = f2bf(v);
                else if (c_bf16)     C16[(long long)row * ldc + col] = f2bf(v);
                else                 C32[(long long)row * ldc + col] = v;
            }
        }
    }
}

// ---------------------------------------------------------------- fused flash attention, key-split over blockIdx.z
// 3-buffer, depth-2 prefetch (covers ~900cy HBM latency per tile).
// Emits UNNORMALIZED O~ (f32) + per-row (m,l); combine kernel merges.
template<int CAUSAL>
__global__ __launch_bounds__(256) void attn_split(
    const u16* __restrict__ Qg, int ldq,
    const u16* __restrict__ Kg, int ldk,
    const u16* __restrict__ VT,   // [*][SEQ], head-major rows
    float* __restrict__ Op,       // [2][SEQ][DMODEL]
    float* __restrict__ Ml)       // [2][NHEAD][SEQ][2]
{
    const int h  = blockIdx.y;
    const int qt = blockIdx.x;
    const int s  = blockIdx.z;
    const int q0 = qt * 64;
    const int t = threadIdx.x, lane = t & 63, w = t >> 6;

    const int last = CAUSAL ? qt : (SEQ / 64 - 1);

    if (CAUSAL && s > last) {
        for (int e = t; e < 64 * 64; e += 256) {
            int r = e >> 6, c = e & 63;
            Op[(long long)s * AC_ELEMS + (long long)(q0 + r) * DMODEL + h * 64 + c] = 0.0f;
        }
        if (t < 64) {
            long long mi = (((long long)s * NHEAD + h) * SEQ + q0 + t) * 2;
            Ml[mi] = -3.0e38f; Ml[mi + 1] = 0.0f;
        }
        return;
    }

    __shared__ __align__(16) u16 Ks[3][64 * 64];
    __shared__ __align__(16) u16 Vs[3][64 * 64];
    __shared__ __align__(16) u16 Ps[4][16 * 64];

    short8 qf[2];
    {
        int qrow = q0 + w * 16 + (lane & 15);
        const u16* qp = Qg + (long long)qrow * ldq + h * DHEAD + ((lane >> 4) << 3);
        qf[0] = *(const short8*)qp;
        qf[1] = *(const short8*)(qp + 32);
    }

    auto stage = [&](int b, int kt) {
#pragma unroll
        for (int i = 0; i < 2; ++i) {
            int LL = i * 256 + t;
            int row = LL >> 3, cp = LL & 7, c = cp ^ (row & 7);
            async16(Kg + (long long)(kt * 64 + row) * ldk + h * DHEAD + (c << 3),
                    &Ks[b][(i * 256 + w * 64) * 8]);
            async16(VT + (long long)(h * DHEAD + row) * SEQ + kt * 64 + (c << 3),
                    &Vs[b][(i * 256 + w * 64) * 8]);
        }
    };

    f32x4 o_acc[4] = {};
    float m_r[4], l_r[4];
#pragma unroll
    for (int r = 0; r < 4; ++r) { m_r[r] = -3.0e38f; l_r[r] = 0.f; }

    stage(0, s);
    if (s + 2 <= last) stage(1, s + 2);

    const int nt = (last - s) / 2 + 1;
    for (int i = 0; i < nt; ++i) {
        const int kt = s + 2 * i;
        const int buf = i % 3;
        if (kt + 4 <= last) { stage((i + 2) % 3, kt + 4); waitv<8>(); }
        else if (kt + 2 <= last) waitv<4>();
        else                     waitv<0>();
        bar();

        f32x4 sv[4] = {};
#pragma unroll
        for (int kk = 0; kk < 2; ++kk) {
            const int cb = kk * 4 + (lane >> 4);
#pragma unroll
            for (int n = 0; n < 4; ++n) {
                int R = n * 16 + (lane & 15);
                short8 kf = *(const short8*)&Ks[buf][R * 64 + ((cb ^ (R & 7)) << 3)];
                sv[n] = __builtin_amdgcn_mfma_f32_16x16x32_bf16(qf[kk], kf, sv[n], 0, 0, 0);
            }
        }

#pragma unroll
        for (int n = 0; n < 4; ++n) {
            int keyl = n * 16 + (lane & 15);
#pragma unroll
            for (int r = 0; r < 4; ++r) {
                float v = sv[n][r] * 0.125f;
                if (CAUSAL && kt == qt) {
                    int ql = w * 16 + ((lane >> 4) << 2) + r;
                    if (keyl > ql) v -= 10000.0f;
                }
                sv[n][r] = v;
            }
        }

#pragma unroll
        for (int r = 0; r < 4; ++r) {
            float vm = fmaxf(fmaxf(sv[0][r], sv[1][r]), fmaxf(sv[2][r], sv[3][r]));
            vm = fmaxf(vm, __shfl_xor(vm, 1));
            vm = fmaxf(vm, __shfl_xor(vm, 2));
            vm = fmaxf(vm, __shfl_xor(vm, 4));
            vm = fmaxf(vm, __shfl_xor(vm, 8));
            float mn = fmaxf(m_r[r], vm);
            float sf = __expf(m_r[r] - mn);
            m_r[r] = mn;
            float rowsum = 0.f;
#pragma unroll
            for (int n = 0; n < 4; ++n) {
                float p = __expf(sv[n][r] - mn);
                sv[n][r] = p;
                rowsum += p;
            }
            rowsum += __shfl_xor(rowsum, 1);
            rowsum += __shfl_xor(rowsum, 2);
            rowsum += __shfl_xor(rowsum, 4);
            rowsum += __shfl_xor(rowsum, 8);
            l_r[r] = l_r[r] * sf + rowsum;
#pragma unroll
            for (int d = 0; d < 4; ++d) o_acc[d][r] *= sf;
        }

#pragma unroll
        for (int n = 0; n < 4; ++n) {
            int jh = lane & 7;
            int chunk = n * 2 + ((lane & 15) >> 3);
#pragma unroll
            for (int r = 0; r < 4; ++r) {
                int q = ((lane >> 4) << 2) + r;
                Ps[w][q * 64 + ((chunk ^ (q & 7)) << 3) + jh] = f2bf(sv[n][r]);
            }
        }

#pragma unroll
        for (int kk = 0; kk < 2; ++kk) {
            int q = lane & 15;
            int chunk = (lane >> 4) + kk * 4;
            short8 pf = *(const short8*)&Ps[w][q * 64 + ((chunk ^ (q & 7)) << 3)];
            const int cb = kk * 4 + (lane >> 4);
#pragma unroll
            for (int d = 0; d < 4; ++d) {
                int R = d * 16 + (lane & 15);
                short8 vf = *(const short8*)&Vs[buf][R * 64 + ((cb ^ (R & 7)) << 3)];
                o_acc[d] = __builtin_amdgcn_mfma_f32_16x16x32_bf16(pf, vf, o_acc[d], 0, 0, 0);
            }
        }
        bar();
    }

#pragma unroll
    for (int r = 0; r < 4; ++r) {
        int row = q0 + w * 16 + ((lane >> 4) << 2) + r;
#pragma unroll
        for (int d = 0; d < 4; ++d) {
            int col = h * DHEAD + d * 16 + (lane & 15);
            Op[(long long)s * AC_ELEMS + (long long)row * DMODEL + col] = o_acc[d][r];
        }
        if ((lane & 15) == 0) {
            long long mi = (((long long)s * NHEAD + h) * SEQ + row) * 2;
            Ml[mi] = m_r[r]; Ml[mi + 1] = l_r[r];
        }
    }
}

// ---------------------------------------------------------------- combine split partials -> bf16 O
__global__ __launch_bounds__(192) void attn_combine(const float* __restrict__ Op,
                                                    const float* __restrict__ Ml,
                                                    u16* __restrict__ O) {
    const int row = blockIdx.x;
    const int c0 = threadIdx.x * 4;
    const int h = c0 >> 6;
    long long m0i = (((long long)0 * NHEAD + h) * SEQ + row) * 2;
    long long m1i = (((long long)1 * NHEAD + h) * SEQ + row) * 2;
    float m0 = Ml[m0i], l0 = Ml[m0i + 1];
    float m1 = Ml[m1i], l1 = Ml[m1i + 1];
    float M = fmaxf(m0, m1);
    float w0 = __expf(m0 - M), w1 = __expf(m1 - M);
    float inv = 1.0f / (w0 * l0 + w1 * l1);
    float4 a = *(const float4*)&Op[(long long)row * DMODEL + c0];
    float4 b = *(const float4*)&Op[(long long)AC_ELEMS + (long long)row * DMODEL + c0];
    ushort4 o;
    o.x = f2bf((w0 * a.x + w1 * b.x) * inv);
    o.y = f2bf((w0 * a.y + w1 * b.y) * inv);
    o.z = f2bf((w0 * a.z + w1 * b.z) * inv);
    o.w = f2bf((w0 * a.w + w1 * b.w) * inv);
    *(ushort4*)&O[(long long)row * DMODEL + c0] = o;
}

// ---------------------------------------------------------------- f32 row softmax (final)
__global__ __launch_bounds__(256) void softmax_f32(const float* __restrict__ in,
                                                   float* __restrict__ out, int width) {
    const float* row = in + (long long)blockIdx.x * width;
    float* orow = out + (long long)blockIdx.x * width;
    int tid = threadIdx.x;
    __shared__ float red[256];
    int nf4 = width >> 2;
    float4 v = {-1e30f, -1e30f, -1e30f, -1e30f};
    if (tid < nf4) v = ((const float4*)row)[tid];
    float mx = fmaxf(fmaxf(v.x, v.y), fmaxf(v.z, v.w));
    mx = block_max(mx, red);
    float4 e = {0.f, 0.f, 0.f, 0.f};
    float s = 0.f;
    if (tid < nf4) {
        e.x = __expf(v.x - mx); e.y = __expf(v.y - mx);
        e.z = __expf(v.z - mx); e.w = __expf(v.w - mx);
        s = e.x + e.y + e.z + e.w;
    }
    s = block_sum(s, red);
    float inv = 1.0f / s;
    if (tid < nf4) {
        e.x *= inv; e.y *= inv; e.z *= inv; e.w *= inv;
        ((float4*)orow)[tid] = e;
    }
}

// ---------------------------------------------------------------- wave-per-row LN: x = LN(x + fx (+fx2)); emits f32 + bf16
__global__ __launch_bounds__(256) void ln_res_kernel(float* __restrict__ x,
                                                     const float* __restrict__ fx,
                                                     const float* __restrict__ fx2,
                                                     int n2,
                                                     const float* __restrict__ ga,
                                                     const float* __restrict__ gb,
                                                     u16* __restrict__ xb) {
    const int w = threadIdx.x >> 6, lane = threadIdx.x & 63;
    const long long row = (long long)blockIdx.x * 4 + w;
    float* xr = x + row * DMODEL;
    const float* fr = fx + row * DMODEL;
    const float* f2r = fx2 ? fx2 + row * DMODEL : nullptr;
    u16* xbr = xb + row * DMODEL;

    float4 t[3];
    float sum = 0.f;
#pragma unroll
    for (int c = 0; c < 3; ++c) {
        int idx = c * 256 + lane * 4;
        float4 a = *(const float4*)(xr + idx);
        float4 f = *(const float4*)(fr + idx);
        t[c].x = a.x + f.x; t[c].y = a.y + f.y; t[c].z = a.z + f.z; t[c].w = a.w + f.w;
        if (n2) {
            float4 g = *(const float4*)(f2r + idx);
            t[c].x += g.x; t[c].y += g.y; t[c].z += g.z; t[c].w += g.w;
        }
        sum += t[c].x + t[c].y + t[c].z + t[c].w;
    }
#pragma unroll
    for (int s = 1; s < 64; s <<= 1) sum += __shfl_xor(sum, s);
    float mean = sum * (1.0f / (float)DMODEL);

    float ss = 0.f;
#pragma unroll
    for (int c = 0; c < 3; ++c) {
        float dx = t[c].x - mean, dy = t[c].y - mean, dz = t[c].z - mean, dw = t[c].w - mean;
        ss += dx * dx + dy * dy + dz * dz + dw * dw;
    }
#pragma unroll
    for (int s = 1; s < 64; s <<= 1) ss += __shfl_xor(ss, s);
    float stdv = sqrtf(ss / (float)(DMODEL - 1));
    float inv = 1.0f / (stdv + 1e-6f);

#pragma unroll
    for (int c = 0; c < 3; ++c) {
        int idx = c * 256 + lane * 4;
        float4 A = *(const float4*)(ga + idx);
        float4 B = *(const float4*)(gb + idx);
        float4 o;
        o.x = A.x * (t[c].x - mean) * inv + B.x;
        o.y = A.y * (t[c].y - mean) * inv + B.y;
        o.z = A.z * (t[c].z - mean) * inv + B.z;
        o.w = A.w * (t[c].w - mean) * inv + B.w;
        *(float4*)(xr + idx) = o;
        ushort4 ob;
        ob.x = f2bf(o.x); ob.y = f2bf(o.y); ob.z = f2bf(o.z); ob.w = f2bf(o.w);
        *(ushort4*)(xbr + idx) = ob;
    }
}

// ---------------------------------------------------------------- host
struct GArg {
    const u16* A; int lda;
    const void* B; int ldb; int b_f32;
    const float* bias;
    void* C; int ldc; int c_bf16;
    u16* vt; int vt_col0; int vt_mode;
    int N, M, K; int relu;
};
template<int TM, int TN, int WR, int WC>
static inline void glaunch(hipStream_t st, const GArg& a, int splitk = 1, float* C2 = nullptr) {
    dim3 grid(a.M / TN, a.N / TM, splitk);
    hipLaunchKernelGGL((gemm_mfma<TM, TN, WR, WC>), grid, dim3(WR * WC * 64), 0, st,
                       a.A, a.lda, a.B, a.ldb, a.b_f32, a.bias, a.C, a.ldc, a.c_bf16,
                       C2, a.vt, a.vt_col0, a.vt_mode, a.K / splitk, a.relu);
}

extern "C" void kernel_launch(void* const* d_in, const int* in_sizes, int n_in,
                              void* d_out, int out_size, void* d_ws, size_t ws_size,
                              hipStream_t stream) {
    const float* xl      = (const float*)d_in[0];
    const float* dl      = (const float*)d_in[1];
    const float* pe      = (const float*)d_in[2];
    const float* enc_wq  = (const float*)d_in[3];
    const float* enc_wk  = (const float*)d_in[4];
    const float* enc_wv  = (const float*)d_in[5];
    const float* enc_wo  = (const float*)d_in[6];
    const float* enc_bo  = (const float*)d_in[7];
    const float* enc_lna = (const float*)d_in[8];
    const float* enc_lnb = (const float*)d_in[9];
    const float* enc_w1  = (const float*)d_in[10];
    const float* enc_b1  = (const float*)d_in[11];
    const float* enc_w2  = (const float*)d_in[12];
    const float* enc_b2  = (const float*)d_in[13];
    const float* dec_wq  = (const float*)d_in[14];
    const float* dec_wk  = (const float*)d_in[15];
    const float* dec_wv  = (const float*)d_in[16];
    const float* dec_wo  = (const float*)d_in[17];
    const float* dec_bo  = (const float*)d_in[18];
    const float* dec_cwq = (const float*)d_in[19];
    const float* dec_cwk = (const float*)d_in[20];
    const float* dec_cwv = (const float*)d_in[21];
    const float* dec_cwo = (const float*)d_in[22];
    const float* dec_cbo = (const float*)d_in[23];
    const float* dec_lna = (const float*)d_in[24];
    const float* dec_lnb = (const float*)d_in[25];
    const float* dec_w1  = (const float*)d_in[26];
    const float* dec_b1  = (const float*)d_in[27];
    const float* dec_w2  = (const float*)d_in[28];
    const float* dec_b2  = (const float*)d_in[29];

    const long long AC   = AC_ELEMS;
    const long long DD   = (long long)DMODEL * DMODEL;
    const long long WH   = (long long)HIDDEN * DMODEL;
    const long long QKVC = (long long)SEQ * 3 * DMODEL;
    const long long SH   = (long long)SEQ * HIDDEN;

    float* mbuf  = (float*)d_ws;
    float* xbuf  = mbuf + AC;
    float* fbuf  = xbuf + AC;
    float* fbuf2 = fbuf + AC;                  // split-K partial
    float* Opart = fbuf2 + AC;                 // [2][SEQ][DMODEL]
    float* Ml    = Opart + 2 * AC;             // [2][NHEAD][SEQ][2]
    u16* u = (u16*)(Ml + 2LL * NHEAD * SEQ * 2);
    u16* mb16 = u;  u += AC;
    u16* xb16 = u;  u += AC;
    u16* qkvb = u;  u += QKVC;      // [1024][2304]
    u16* vt   = u;  u += AC;        // self-attn V^T [768][1024]
    u16* ob   = u;  u += AC;        // attention out (combined, bf16)
    u16* hb   = u;  u += SH;        // ffn hidden
    u16* ckb  = u;  u += 12LL * AC; // cross K|V columns [1024][9216] (v cols diverted)
    u16* cvb  = u;  u += 6LL * AC;  // cross V^T [6][768][1024]

    // converted bf16 weights
    u16* W = u;
    long long woff = 0;
    const long long W_ENC_QKV = woff; woff += 18 * DD;
    const long long W_ENC_WO  = woff; woff += 6 * DD;
    const long long W_ENC_W1  = woff; woff += 6 * WH;
    const long long W_ENC_W2  = woff; woff += 6 * WH;
    const long long W_DEC_QKV = woff; woff += 18 * DD;
    const long long W_DEC_CQ  = woff; woff += 6 * DD;
    const long long W_DEC_CKV = woff; woff += 12 * DD;   // [l][k|v]
    const long long W_DEC_WO  = woff; woff += 6 * DD;
    const long long W_DEC_CWO = woff; woff += 6 * DD;
    const long long W_DEC_W1  = woff; woff += 6 * WH;
    const long long W_DEC_W2  = woff; woff += 6 * WH;
    const long long need = (long long)((char*)(W + woff) - (char*)d_ws);
    const bool conv = ((long long)ws_size >= need);

    if (conv) {
        CvtDesc dsc;
        struct Tmp { const float* src; long long dst; long long per; long long sls; long long dls; int L; };
        Tmp tmp[16] = {
            { enc_wq,  W_ENC_QKV + 0 * DD, DD, DD, 3 * DD, NLAYER },
            { enc_wk,  W_ENC_QKV + 1 * DD, DD, DD, 3 * DD, NLAYER },
            { enc_wv,  W_ENC_QKV + 2 * DD, DD, DD, 3 * DD, NLAYER },
            { enc_wo,  W_ENC_WO,  6 * DD, 0, 0, 1 },
            { enc_w1,  W_ENC_W1,  6 * WH, 0, 0, 1 },
            { enc_w2,  W_ENC_W2,  6 * WH, 0, 0, 1 },
            { dec_wq,  W_DEC_QKV + 0 * DD, DD, DD, 3 * DD, NLAYER },
            { dec_wk,  W_DEC_QKV + 1 * DD, DD, DD, 3 * DD, NLAYER },
            { dec_wv,  W_DEC_QKV + 2 * DD, DD, DD, 3 * DD, NLAYER },
            { dec_cwq, W_DEC_CQ,  6 * DD, 0, 0, 1 },
            { dec_cwk, W_DEC_CKV + 0 * DD, DD, DD, 2 * DD, NLAYER },
            { dec_cwv, W_DEC_CKV + 1 * DD, DD, DD, 2 * DD, NLAYER },
            { dec_wo,  W_DEC_WO,  6 * DD, 0, 0, 1 },
            { dec_cwo, W_DEC_CWO, 6 * DD, 0, 0, 1 },
            { dec_w1,  W_DEC_W1,  6 * WH, 0, 0, 1 },
            { dec_w2,  W_DEC_W2,  6 * WH, 0, 0, 1 },
        };
        int total = 0;
        for (int i = 0; i < 16; ++i) {
            dsc.seg[i] = { tmp[i].src, tmp[i].dst, (int)(tmp[i].per / 4096), tmp[i].sls, tmp[i].dls };
            dsc.blkStart[i] = total;
            total += (int)(tmp[i].per / 4096) * tmp[i].L;
        }
        dsc.blkStart[16] = total;
        hipLaunchKernelGGL(cvt_all, dim3(total), dim3(256), 0, stream, dsc, W);
    }

    hipLaunchKernelGGL(add_pe2, dim3((int)(AC / 256), 2), dim3(256), 0, stream,
                       xl, dl, pe, mbuf, xbuf, mb16, xb16, (int)AC);

    auto attn = [&](int causal, const u16* Qg, int ldq, const u16* Kg, int ldk, const u16* VT) {
        dim3 grid(SEQ / 64, NHEAD, 2);
        if (causal)
            hipLaunchKernelGGL((attn_split<1>), grid, dim3(256), 0, stream, Qg, ldq, Kg, ldk, VT, Opart, Ml);
        else
            hipLaunchKernelGGL((attn_split<0>), grid, dim3(256), 0, stream, Qg, ldq, Kg, ldk, VT, Opart, Ml);
        hipLaunchKernelGGL(attn_combine, dim3(SEQ), dim3(192), 0, stream, Opart, Ml, ob);
    };

    auto lnres = [&](float* x, const float* fx, const float* fx2, int n2,
                     const float* ga, const float* gb, u16* xb) {
        hipLaunchKernelGGL(ln_res_kernel, dim3(SEQ / 4), dim3(256), 0, stream,
                           x, fx, fx2, n2, ga, gb, xb);
    };

    // ---------------- encoder ----------------
    for (int l = 0; l < NLAYER; ++l) {
        if (conv) {
            GArg qkv = { mb16, DMODEL, W + W_ENC_QKV + l * 3 * DD, DMODEL, 0, nullptr,
                         qkvb, 3 * DMODEL, 1, vt, 2 * DMODEL, 1,
                         SEQ, 3 * DMODEL, DMODEL, 0 };
            glaunch<64, 64, 2, 2>(stream, qkv);
        } else {
            const float* wps[3] = { enc_wq + l * DD, enc_wk + l * DD, enc_wv + l * DD };
            for (int j = 0; j < 3; ++j) {
                GArg a = { mb16, DMODEL, wps[j], DMODEL, 1, nullptr,
                           qkvb + j * DMODEL, 3 * DMODEL, 1,
                           (j == 2) ? vt : nullptr, 0, (j == 2) ? 1 : 0,
                           SEQ, DMODEL, DMODEL, 0 };
                glaunch<32, 32, 1, 1>(stream, a);
            }
        }
        attn(0, qkvb, 3 * DMODEL, qkvb + DMODEL, 3 * DMODEL, vt);
        GArg wo = { ob, DMODEL,
                    conv ? (const void*)(W + W_ENC_WO + l * DD) : (const void*)(enc_wo + l * DD),
                    DMODEL, conv ? 0 : 1, enc_bo + (long long)l * DMODEL,
                    fbuf, DMODEL, 0, nullptr, 0, 0,
                    SEQ, DMODEL, DMODEL, 0 };
        glaunch<32, 32, 1, 1>(stream, wo);
        lnres(mbuf, fbuf, nullptr, 0,
              enc_lna + (long long)(l * 2 + 0) * DMODEL,
              enc_lnb + (long long)(l * 2 + 0) * DMODEL, mb16);
        GArg f1 = { mb16, DMODEL,
                    conv ? (const void*)(W + W_ENC_W1 + l * WH) : (const void*)(enc_w1 + l * WH),
                    DMODEL, conv ? 0 : 1, enc_b1 + (long long)l * HIDDEN,
                    hb, HIDDEN, 1, nullptr, 0, 0,
                    SEQ, HIDDEN, DMODEL, 1 };
        glaunch<64, 64, 2, 2>(stream, f1);
        GArg f2 = { hb, HIDDEN,
                    conv ? (const void*)(W + W_ENC_W2 + l * WH) : (const void*)(enc_w2 + l * WH),
                    HIDDEN, conv ? 0 : 1, enc_b2 + (long long)l * DMODEL,
                    fbuf, DMODEL, 0, nullptr, 0, 0,
                    SEQ, DMODEL, HIDDEN, 0 };
        glaunch<64, 64, 2, 2>(stream, f2, 2, fbuf2);
        lnres(mbuf, fbuf, fbuf2, 1,
              enc_lna + (long long)(l * 2 + 1) * DMODEL,
              enc_lnb + (long long)(l * 2 + 1) * DMODEL, mb16);
    }

    // batched cross K/V for ALL decoder layers (encoder output is final here)
    if (conv) {
        GArg ckv = { mb16, DMODEL, W + W_DEC_CKV, DMODEL, 0, nullptr,
                     ckb, 12 * DMODEL, 1, cvb, 0, 2,
                     SEQ, 12 * DMODEL, DMODEL, 0 };
        glaunch<64, 64, 2, 2>(stream, ckv);
    }

    // ---------------- decoder ----------------
    for (int l = 0; l < NLAYER; ++l) {
        // self attention (causal)
        if (conv) {
            GArg qkv = { xb16, DMODEL, W + W_DEC_QKV + l * 3 * DD, DMODEL, 0, nullptr,
                         qkvb, 3 * DMODEL, 1, vt, 2 * DMODEL, 1,
                         SEQ, 3 * DMODEL, DMODEL, 0 };
            glaunch<64, 64, 2, 2>(stream, qkv);
        } else {
            const float* wps[3] = { dec_wq + l * DD, dec_wk + l * DD, dec_wv + l * DD };
            for (int j = 0; j < 3; ++j) {
                GArg a = { xb16, DMODEL, wps[j], DMODEL, 1, nullptr,
                           qkvb + j * DMODEL, 3 * DMODEL, 1,
                           (j == 2) ? vt : nullptr, 0, (j == 2) ? 1 : 0,
                           SEQ, DMODEL, DMODEL, 0 };
                glaunch<32, 32, 1, 1>(stream, a);
            }
        }
        attn(1, qkvb, 3 * DMODEL, qkvb + DMODEL, 3 * DMODEL, vt);
        GArg wo = { ob, DMODEL,
                    conv ? (const void*)(W + W_DEC_WO + l * DD) : (const void*)(dec_wo + l * DD),
                    DMODEL, conv ? 0 : 1, dec_bo + (long long)l * DMODEL,
                    fbuf, DMODEL, 0, nullptr, 0, 0,
                    SEQ, DMODEL, DMODEL, 0 };
        glaunch<32, 32, 1, 1>(stream, wo);
        lnres(xbuf, fbuf, nullptr, 0,
              dec_lna + (long long)(l * 3 + 0) * DMODEL,
              dec_lnb + (long long)(l * 3 + 0) * DMODEL, xb16);

        // cross attention
        if (conv) {
            GArg q = { xb16, DMODEL, W + W_DEC_CQ + l * DD, DMODEL, 0, nullptr,
                       qkvb, 3 * DMODEL, 1, nullptr, 0, 0,
                       SEQ, DMODEL, DMODEL, 0 };
            glaunch<32, 32, 1, 1>(stream, q);
            attn(0, qkvb, 3 * DMODEL, ckb + l * 2 * DMODEL, 12 * DMODEL, cvb + (long long)l * AC);
        } else {
            GArg q = { xb16, DMODEL, dec_cwq + l * DD, DMODEL, 1, nullptr,
                       qkvb, 3 * DMODEL, 1, nullptr, 0, 0,
                       SEQ, DMODEL, DMODEL, 0 };
            glaunch<32, 32, 1, 1>(stream, q);
            GArg ck = { mb16, DMODEL, dec_cwk + l * DD, DMODEL, 1, nullptr,
                        qkvb + DMODEL, 3 * DMODEL, 1, nullptr, 0, 0,
                        SEQ, DMODEL, DMODEL, 0 };
            glaunch<32, 32, 1, 1>(stream, ck);
            GArg cv = { mb16, DMODEL, dec_cwv + l * DD, DMODEL, 1, nullptr,
                        qkvb + 2 * DMODEL, 3 * DMODEL, 1, vt, 0, 1,
                        SEQ, DMODEL, DMODEL, 0 };
            glaunch<32, 32, 1, 1>(stream, cv);
            attn(0, qkvb, 3 * DMODEL, qkvb + DMODEL, 3 * DMODEL, vt);
        }
        GArg cwo = { ob, DMODEL,
                     conv ? (const void*)(W + W_DEC_CWO + l * DD) : (const void*)(dec_cwo + l * DD),
                     DMODEL, conv ? 0 : 1, dec_cbo + (long long)l * DMODEL,
                     fbuf, DMODEL, 0, nullptr, 0, 0,
                     SEQ, DMODEL, DMODEL, 0 };
        glaunch<32, 32, 1, 1>(stream, cwo);
        lnres(xbuf, fbuf, nullptr, 0,
              dec_lna + (long long)(l * 3 + 1) * DMODEL,
              dec_lnb + (long long)(l * 3 + 1) * DMODEL, xb16);

        // FFN
        GArg f1 = { xb16, DMODEL,
                    conv ? (const void*)(W + W_DEC_W1 + l * WH) : (const void*)(dec_w1 + l * WH),
                    DMODEL, conv ? 0 : 1, dec_b1 + (long long)l * HIDDEN,
                    hb, HIDDEN, 1, nullptr, 0, 0,
                    SEQ, HIDDEN, DMODEL, 1 };
        glaunch<64, 64, 2, 2>(stream, f1);
        GArg f2 = { hb, HIDDEN,
                    conv ? (const void*)(W + W_DEC_W2 + l * WH) : (const void*)(dec_w2 + l * WH),
                    HIDDEN, conv ? 0 : 1, dec_b2 + (long long)l * DMODEL,
                    fbuf, DMODEL, 0, nullptr, 0, 0,
                    SEQ, DMODEL, HIDDEN, 0 };
        glaunch<64, 64, 2, 2>(stream, f2, 2, fbuf2);
        lnres(xbuf, fbuf, fbuf2, 1,
              dec_lna + (long long)(l * 3 + 2) * DMODEL,
              dec_lnb + (long long)(l * 3 + 2) * DMODEL, xb16);
    }

    hipLaunchKernelGGL(softmax_f32, dim3(SEQ), dim3(256), 0, stream, xbuf, (float*)d_out, DMODEL);
}

// Round 20
// 1504.696 us; speedup vs baseline: 1.0880x; 1.0880x over previous
//
#include <hip/hip_runtime.h>
#include <math.h>

#define DMODEL 768
#define NHEAD 12
#define DHEAD 64
#define HIDDEN 3072
#define NLAYER 6
#define SEQ 1024
#define AC_ELEMS (SEQ * DMODEL)

typedef unsigned short u16;
typedef __attribute__((ext_vector_type(8))) short short8;
typedef __attribute__((ext_vector_type(4))) float f32x4;

__device__ __forceinline__ u16 f2bf(float f) {
    union { float f; unsigned u; } v; v.f = f;
    unsigned u = v.u;
    return (u16)((u + 0x7fffu + ((u >> 16) & 1u)) >> 16);
}
__device__ __forceinline__ float bf2f(u16 b) {
    union { unsigned u; float f; } v; v.u = ((unsigned)b) << 16; return v.f;
}

// async global->LDS, 16B/lane; LDS base wave-uniform (HW adds lane*16)
__device__ __forceinline__ void async16(const void* g, void* l) {
    __builtin_amdgcn_global_load_lds(
        (const __attribute__((address_space(1))) unsigned int*)g,
        (__attribute__((address_space(3))) unsigned int*)l, 16, 0, 0);
}

// counted vmcnt wait + scheduling fence (rule #18)
template<int N> __device__ __forceinline__ void waitv() {
    asm volatile("s_waitcnt vmcnt(%0)" :: "n"(N) : "memory");
    __builtin_amdgcn_sched_barrier(0);
}
__device__ __forceinline__ void drain_all() {
    asm volatile("s_waitcnt vmcnt(0) lgkmcnt(0)" ::: "memory");
    __builtin_amdgcn_sched_barrier(0);
}
__device__ __forceinline__ void bar() {
    __builtin_amdgcn_sched_barrier(0);
    __builtin_amdgcn_s_barrier();
    __builtin_amdgcn_sched_barrier(0);
}

// ---------------------------------------------------------------- reductions
__device__ __forceinline__ float block_sum(float v, float* red) {
    int tid = threadIdx.x;
    red[tid] = v;
    __syncthreads();
#pragma unroll
    for (int s = 128; s > 0; s >>= 1) {
        if (tid < s) red[tid] += red[tid + s];
        __syncthreads();
    }
    float r = red[0];
    __syncthreads();
    return r;
}
__device__ __forceinline__ float block_max(float v, float* red) {
    int tid = threadIdx.x;
    red[tid] = v;
    __syncthreads();
#pragma unroll
    for (int s = 128; s > 0; s >>= 1) {
        if (tid < s) red[tid] = fmaxf(red[tid], red[tid + s]);
        __syncthreads();
    }
    float r = red[0];
    __syncthreads();
    return r;
}

// ---------------------------------------------------------------- small kernels
__global__ __launch_bounds__(256) void add_pe2(const float* __restrict__ a0,
                                               const float* __restrict__ a1,
                                               const float* __restrict__ pe,
                                               float* __restrict__ o0,
                                               float* __restrict__ o1,
                                               u16* __restrict__ ob0,
                                               u16* __restrict__ ob1, int n) {
    int i = blockIdx.x * 256 + threadIdx.x;
    if (i >= n) return;
    const float* a = blockIdx.y ? a1 : a0;
    float* o = blockIdx.y ? o1 : o0;
    u16* ob = blockIdx.y ? ob1 : ob0;
    float v = a[i] + pe[i];
    o[i] = v; ob[i] = f2bf(v);
}

// one-launch weight conversion: 16 segments, 4096 f32/block, 32-bit index math.
// Nontemporal loads: f32 src is read-once-ever -> don't pollute L2/L3.
struct CvtSeg { const float* src; long long dst; int bpl; long long sls; long long dls; };
struct CvtDesc { CvtSeg seg[16]; int blkStart[17]; };

__global__ __launch_bounds__(256) void cvt_all(CvtDesc d, u16* __restrict__ W) {
    int b = blockIdx.x, s = 0;
#pragma unroll 1
    while (b >= d.blkStart[s + 1]) ++s;
    const CvtSeg g = d.seg[s];
    int rel = b - d.blkStart[s];
    int layer = rel / g.bpl;
    int blkInL = rel - layer * g.bpl;
    const float* src = g.src + (long long)layer * g.sls + (long long)blkInL * 4096;
    u16* dst = W + g.dst + (long long)layer * g.dls + (long long)blkInL * 4096;
#pragma unroll
    for (int j = 0; j < 4; ++j) {
        int idx = (j * 256 + threadIdx.x) * 4;
        f32x4 v = __builtin_nontemporal_load((const f32x4*)(src + idx));
        ushort4 o;
        o.x = f2bf(v.x); o.y = f2bf(v.y); o.z = f2bf(v.z); o.w = f2bf(v.w);
        *(ushort4*)(dst + idx) = o;
    }
}

// ---------------------------------------------------------------- MFMA GEMM
// DB-buffer (3 when LDS fits, else 2), counted vmcnt (pure-bf16 path).
// C[N x M] = A[N x K](bf16) * B[M x K]^T (+bias) (+relu)
// B: bf16 (async) or f32 (reg-staged convert).
// blockIdx.z = K-split; z>0 writes f32 partial to C2 + (z-1)*AC.
// vt_mode: 0 none; 1 cols>=vt_col0 transposed to vt_out; 2 periodic k|v (1536):
//          rem=col%1536>=768 -> vt_out[((col/1536)*768+rem-768)*SEQ+row].
template<int TM, int TN, int WR, int WC>
__global__ __launch_bounds__(WR * WC * 64) void gemm_mfma(
    const u16* __restrict__ A, int lda,
    const void* __restrict__ Bp, int ldb, int b_f32,
    const float* __restrict__ bias,
    void* __restrict__ Cp, int ldc, int c_bf16,
    float* __restrict__ C2,
    u16* __restrict__ vt_out, int vt_col0, int vt_mode,
    int Ksub, int relu)
{
    constexpr int T  = WR * WC * 64;
    constexpr bool MW = (WR * WC) > 1;
    constexpr int FM = TM / (WR * 16), FN = TN / (WC * 16);
    constexpr int NA = TM * 8 / T, NB = TN * 8 / T;
    constexpr int LPS = NA + NB;
    constexpr int DB = (3 * (TM + TN) * 64 * 2 <= 65536) ? 3 : 2;
    constexpr int DEPTH = DB - 1;
    __shared__ __align__(16) u16 As[DB][TM * 64];
    __shared__ __align__(16) u16 Bs[DB][TN * 64];

    const int zs = blockIdx.z;
    const u16*   B16 = (const u16*)Bp   + (long long)zs * Ksub;
    const float* B32 = (const float*)Bp + (long long)zs * Ksub;
    A += (long long)zs * Ksub;
    u16*   C16 = (u16*)Cp;
    float* C32 = (float*)Cp;

    const int t = threadIdx.x, lane = t & 63, w = t >> 6;
    const int wy = w / WC, wx = w % WC;
    const int n0 = blockIdx.y * TM, m0 = blockIdx.x * TN;

    auto stage = [&](int b, int k0) {
#pragma unroll
        for (int i = 0; i < NA; ++i) {
            int L = i * T + t;
            int row = L >> 3, cp = L & 7, c = cp ^ (row & 7);
            async16(A + (long long)(n0 + row) * lda + k0 + (c << 3),
                    &As[b][(i * T + w * 64) * 8]);
        }
        if (!b_f32) {
#pragma unroll
            for (int i = 0; i < NB; ++i) {
                int L = i * T + t;
                int row = L >> 3, cp = L & 7, c = cp ^ (row & 7);
                async16(B16 + (long long)(m0 + row) * ldb + k0 + (c << 3),
                        &Bs[b][(i * T + w * 64) * 8]);
            }
        } else {
#pragma unroll
            for (int i = 0; i < NB; ++i) {
                int L = i * T + t;
                int row = L >> 3, cp = L & 7, c = cp ^ (row & 7);
                const float* s = B32 + (long long)(m0 + row) * ldb + k0 + (c << 3);
                float4 x = *(const float4*)s;
                float4 y = *(const float4*)(s + 4);
                uint4 pk;
                pk.x = (unsigned)f2bf(x.x) | ((unsigned)f2bf(x.y) << 16);
                pk.y = (unsigned)f2bf(x.z) | ((unsigned)f2bf(x.w) << 16);
                pk.z = (unsigned)f2bf(y.x) | ((unsigned)f2bf(y.y) << 16);
                pk.w = (unsigned)f2bf(y.z) | ((unsigned)f2bf(y.w) << 16);
                *(uint4*)&Bs[b][row * 64 + cp * 8] = pk;
            }
        }
    };

    const int nk = Ksub / 64;
    stage(0, 0);
    if (DEPTH > 1 && nk > 1) stage(1, 64);

    f32x4 acc[FM][FN] = {};

    for (int tt = 0; tt < nk; ++tt) {
        if (tt + DEPTH < nk) stage((tt + DEPTH) % DB, (tt + DEPTH) * 64);
        if (b_f32) drain_all();
        else {
            int inflight = nk - 1 - tt;
            if (inflight > DEPTH) inflight = DEPTH;
            if (DEPTH == 2) {
                if (inflight == 2)      waitv<2 * LPS>();
                else if (inflight == 1) waitv<LPS>();
                else                    waitv<0>();
            } else {
                if (inflight >= 1) waitv<LPS>();
                else               waitv<0>();
            }
        }
        if (MW) bar();

        const u16* Ac = As[tt % DB];
        const u16* Bc = Bs[tt % DB];
#pragma unroll
        for (int kk = 0; kk < 2; ++kk) {
            short8 af[FM], bfv[FN];
            const int cb = kk * 4 + (lane >> 4);
#pragma unroll
            for (int m = 0; m < FM; ++m) {
                int R = wy * (TM / WR) + m * 16 + (lane & 15);
                af[m] = *(const short8*)&Ac[R * 64 + ((cb ^ (R & 7)) << 3)];
            }
#pragma unroll
            for (int n = 0; n < FN; ++n) {
                int R = wx * (TN / WC) + n * 16 + (lane & 15);
                bfv[n] = *(const short8*)&Bc[R * 64 + ((cb ^ (R & 7)) << 3)];
            }
#pragma unroll
            for (int m = 0; m < FM; ++m)
#pragma unroll
                for (int n = 0; n < FN; ++n)
                    acc[m][n] = __builtin_amdgcn_mfma_f32_16x16x32_bf16(af[m], bfv[n], acc[m][n], 0, 0, 0);
        }
        if (MW) bar();
    }

    const int cj = lane & 15, ci0 = (lane >> 4) << 2;
    const bool z0 = (zs == 0);
    float* C2z = C2 + (long long)(zs - 1) * AC_ELEMS;
#pragma unroll
    for (int m = 0; m < FM; ++m) {
#pragma unroll
        for (int n = 0; n < FN; ++n) {
            int col = m0 + wx * (TN / WC) + n * 16 + cj;
            float bv = (z0 && bias) ? bias[col] : 0.0f;
            long long vtidx = -1;
            if (z0 && vt_mode == 1 && col >= vt_col0) vtidx = (long long)(col - vt_col0) * SEQ;
            else if (z0 && vt_mode == 2) {
                int blk = col / 1536, rem = col % 1536;
                if (rem >= 768) vtidx = ((long long)blk * 768 + rem - 768) * SEQ;
            }
#pragma unroll
            for (int r = 0; r < 4; ++r) {
                int row = n0 + wy * (TM / WR) + m * 16 + ci0 + r;
                float v = acc[m][n][r] + bv;
                if (relu) v = fmaxf(v, 0.0f);
                if (!z0)             C2z[(long long)row * ldc + col] = v;
                else if (vtidx >= 0) vt_out[vtidx + row] = f2bf(v);
                else if (c_bf16)     C16[(long long)row * ldc + col] = f2bf(v);
                else                 C32[(long long)row * ldc + col] = v;
            }
        }
    }
}

// ---------------------------------------------------------------- fused flash attention, key-split over blockIdx.z
// Emits UNNORMALIZED O~ (f32) + per-row (m,l); combine kernel merges.
template<int CAUSAL>
__global__ __launch_bounds__(256) void attn_split(
    const u16* __restrict__ Qg, int ldq,
    const u16* __restrict__ Kg, int ldk,
    const u16* __restrict__ VT,   // [*][SEQ], head-major rows
    float* __restrict__ Op,       // [2][SEQ][DMODEL]
    float* __restrict__ Ml)       // [2][NHEAD][SEQ][2]
{
    const int h  = blockIdx.y;
    const int qt = blockIdx.x;
    const int s  = blockIdx.z;
    const int q0 = qt * 64;
    const int t = threadIdx.x, lane = t & 63, w = t >> 6;

    const int last = CAUSAL ? qt : (SEQ / 64 - 1);

    if (CAUSAL && s > last) {
        for (int e = t; e < 64 * 64; e += 256) {
            int r = e >> 6, c = e & 63;
            Op[(long long)s * AC_ELEMS + (long long)(q0 + r) * DMODEL + h * 64 + c] = 0.0f;
        }
        if (t < 64) {
            long long mi = (((long long)s * NHEAD + h) * SEQ + q0 + t) * 2;
            Ml[mi] = -3.0e38f; Ml[mi + 1] = 0.0f;
        }
        return;
    }

    __shared__ __align__(16) u16 Ks[2][64 * 64];
    __shared__ __align__(16) u16 Vs[2][64 * 64];
    __shared__ __align__(16) u16 Ps[4][16 * 64];

    short8 qf[2];
    {
        int qrow = q0 + w * 16 + (lane & 15);
        const u16* qp = Qg + (long long)qrow * ldq + h * DHEAD + ((lane >> 4) << 3);
        qf[0] = *(const short8*)qp;
        qf[1] = *(const short8*)(qp + 32);
    }

    auto stage = [&](int b, int kt) {
#pragma unroll
        for (int i = 0; i < 2; ++i) {
            int LL = i * 256 + t;
            int row = LL >> 3, cp = LL & 7, c = cp ^ (row & 7);
            async16(Kg + (long long)(kt * 64 + row) * ldk + h * DHEAD + (c << 3),
                    &Ks[b][(i * 256 + w * 64) * 8]);
            async16(VT + (long long)(h * DHEAD + row) * SEQ + kt * 64 + (c << 3),
                    &Vs[b][(i * 256 + w * 64) * 8]);
        }
    };

    f32x4 o_acc[4] = {};
    float m_r[4], l_r[4];
#pragma unroll
    for (int r = 0; r < 4; ++r) { m_r[r] = -3.0e38f; l_r[r] = 0.f; }

    stage(0, s);

    int buf = 0;
    for (int kt = s; kt <= last; kt += 2) {
        if (kt + 2 <= last) { stage(buf ^ 1, kt + 2); waitv<4>(); }
        else                { waitv<0>(); }
        bar();

        f32x4 sv[4] = {};
#pragma unroll
        for (int kk = 0; kk < 2; ++kk) {
            const int cb = kk * 4 + (lane >> 4);
#pragma unroll
            for (int n = 0; n < 4; ++n) {
                int R = n * 16 + (lane & 15);
                short8 kf = *(const short8*)&Ks[buf][R * 64 + ((cb ^ (R & 7)) << 3)];
                sv[n] = __builtin_amdgcn_mfma_f32_16x16x32_bf16(qf[kk], kf, sv[n], 0, 0, 0);
            }
        }

#pragma unroll
        for (int n = 0; n < 4; ++n) {
            int keyl = n * 16 + (lane & 15);
#pragma unroll
            for (int r = 0; r < 4; ++r) {
                float v = sv[n][r] * 0.125f;
                if (CAUSAL && kt == qt) {
                    int ql = w * 16 + ((lane >> 4) << 2) + r;
                    if (keyl > ql) v -= 10000.0f;
                }
                sv[n][r] = v;
            }
        }

#pragma unroll
        for (int r = 0; r < 4; ++r) {
            float vm = fmaxf(fmaxf(sv[0][r], sv[1][r]), fmaxf(sv[2][r], sv[3][r]));
            vm = fmaxf(vm, __shfl_xor(vm, 1));
            vm = fmaxf(vm, __shfl_xor(vm, 2));
            vm = fmaxf(vm, __shfl_xor(vm, 4));
            vm = fmaxf(vm, __shfl_xor(vm, 8));
            float mn = fmaxf(m_r[r], vm);
            float sf = __expf(m_r[r] - mn);
            m_r[r] = mn;
            float rowsum = 0.f;
#pragma unroll
            for (int n = 0; n < 4; ++n) {
                float p = __expf(sv[n][r] - mn);
                sv[n][r] = p;
                rowsum += p;
            }
            rowsum += __shfl_xor(rowsum, 1);
            rowsum += __shfl_xor(rowsum, 2);
            rowsum += __shfl_xor(rowsum, 4);
            rowsum += __shfl_xor(rowsum, 8);
            l_r[r] = l_r[r] * sf + rowsum;
#pragma unroll
            for (int d = 0; d < 4; ++d) o_acc[d][r] *= sf;
        }

#pragma unroll
        for (int n = 0; n < 4; ++n) {
            int jh = lane & 7;
            int chunk = n * 2 + ((lane & 15) >> 3);
#pragma unroll
            for (int r = 0; r < 4; ++r) {
                int q = ((lane >> 4) << 2) + r;
                Ps[w][q * 64 + ((chunk ^ (q & 7)) << 3) + jh] = f2bf(sv[n][r]);
            }
        }

#pragma unroll
        for (int kk = 0; kk < 2; ++kk) {
            int q = lane & 15;
            int chunk = (lane >> 4) + kk * 4;
            short8 pf = *(const short8*)&Ps[w][q * 64 + ((chunk ^ (q & 7)) << 3)];
            const int cb = kk * 4 + (lane >> 4);
#pragma unroll
            for (int d = 0; d < 4; ++d) {
                int R = d * 16 + (lane & 15);
                short8 vf = *(const short8*)&Vs[buf][R * 64 + ((cb ^ (R & 7)) << 3)];
                o_acc[d] = __builtin_amdgcn_mfma_f32_16x16x32_bf16(pf, vf, o_acc[d], 0, 0, 0);
            }
        }
        bar();
        buf ^= 1;
    }

#pragma unroll
    for (int r = 0; r < 4; ++r) {
        int row = q0 + w * 16 + ((lane >> 4) << 2) + r;
#pragma unroll
        for (int d = 0; d < 4; ++d) {
            int col = h * DHEAD + d * 16 + (lane & 15);
            Op[(long long)s * AC_ELEMS + (long long)row * DMODEL + col] = o_acc[d][r];
        }
        if ((lane & 15) == 0) {
            long long mi = (((long long)s * NHEAD + h) * SEQ + row) * 2;
            Ml[mi] = m_r[r]; Ml[mi + 1] = l_r[r];
        }
    }
}

// ---------------------------------------------------------------- combine split partials -> bf16 O
__global__ __launch_bounds__(192) void attn_combine(const float* __restrict__ Op,
                                                    const float* __restrict__ Ml,
                                                    u16* __restrict__ O) {
    const int row = blockIdx.x;
    const int c0 = threadIdx.x * 4;
    const int h = c0 >> 6;
    long long m0i = (((long long)0 * NHEAD + h) * SEQ + row) * 2;
    long long m1i = (((long long)1 * NHEAD + h) * SEQ + row) * 2;
    float m0 = Ml[m0i], l0 = Ml[m0i + 1];
    float m1 = Ml[m1i], l1 = Ml[m1i + 1];
    float M = fmaxf(m0, m1);
    float w0 = __expf(m0 - M), w1 = __expf(m1 - M);
    float inv = 1.0f / (w0 * l0 + w1 * l1);
    float4 a = *(const float4*)&Op[(long long)row * DMODEL + c0];
    float4 b = *(const float4*)&Op[(long long)AC_ELEMS + (long long)row * DMODEL + c0];
    ushort4 o;
    o.x = f2bf((w0 * a.x + w1 * b.x) * inv);
    o.y = f2bf((w0 * a.y + w1 * b.y) * inv);
    o.z = f2bf((w0 * a.z + w1 * b.z) * inv);
    o.w = f2bf((w0 * a.w + w1 * b.w) * inv);
    *(ushort4*)&O[(long long)row * DMODEL + c0] = o;
}

// ---------------------------------------------------------------- f32 row softmax (final)
__global__ __launch_bounds__(256) void softmax_f32(const float* __restrict__ in,
                                                   float* __restrict__ out, int width) {
    const float* row = in + (long long)blockIdx.x * width;
    float* orow = out + (long long)blockIdx.x * width;
    int tid = threadIdx.x;
    __shared__ float red[256];
    int nf4 = width >> 2;
    float4 v = {-1e30f, -1e30f, -1e30f, -1e30f};
    if (tid < nf4) v = ((const float4*)row)[tid];
    float mx = fmaxf(fmaxf(v.x, v.y), fmaxf(v.z, v.w));
    mx = block_max(mx, red);
    float4 e = {0.f, 0.f, 0.f, 0.f};
    float s = 0.f;
    if (tid < nf4) {
        e.x = __expf(v.x - mx); e.y = __expf(v.y - mx);
        e.z = __expf(v.z - mx); e.w = __expf(v.w - mx);
        s = e.x + e.y + e.z + e.w;
    }
    s = block_sum(s, red);
    float inv = 1.0f / s;
    if (tid < nf4) {
        e.x *= inv; e.y *= inv; e.z *= inv; e.w *= inv;
        ((float4*)orow)[tid] = e;
    }
}

// ---------------------------------------------------------------- wave-per-row LN: x = LN(x + fx (+fx2)); emits f32 + bf16
__global__ __launch_bounds__(256) void ln_res_kernel(float* __restrict__ x,
                                                     const float* __restrict__ fx,
                                                     const float* __restrict__ fx2,
                                                     int n2,
                                                     const float* __restrict__ ga,
                                                     const float* __restrict__ gb,
                                                     u16* __restrict__ xb) {
    const int w = threadIdx.x >> 6, lane = threadIdx.x & 63;
    const long long row = (long long)blockIdx.x * 4 + w;
    float* xr = x + row * DMODEL;
    const float* fr = fx + row * DMODEL;
    const float* f2r = fx2 ? fx2 + row * DMODEL : nullptr;
    u16* xbr = xb + row * DMODEL;

    float4 t[3];
    float sum = 0.f;
#pragma unroll
    for (int c = 0; c < 3; ++c) {
        int idx = c * 256 + lane * 4;
        float4 a = *(const float4*)(xr + idx);
        float4 f = *(const float4*)(fr + idx);
        t[c].x = a.x + f.x; t[c].y = a.y + f.y; t[c].z = a.z + f.z; t[c].w = a.w + f.w;
        if (n2) {
            float4 g = *(const float4*)(f2r + idx);
            t[c].x += g.x; t[c].y += g.y; t[c].z += g.z; t[c].w += g.w;
        }
        sum += t[c].x + t[c].y + t[c].z + t[c].w;
    }
#pragma unroll
    for (int s = 1; s < 64; s <<= 1) sum += __shfl_xor(sum, s);
    float mean = sum * (1.0f / (float)DMODEL);

    float ss = 0.f;
#pragma unroll
    for (int c = 0; c < 3; ++c) {
        float dx = t[c].x - mean, dy = t[c].y - mean, dz = t[c].z - mean, dw = t[c].w - mean;
        ss += dx * dx + dy * dy + dz * dz + dw * dw;
    }
#pragma unroll
    for (int s = 1; s < 64; s <<= 1) ss += __shfl_xor(ss, s);
    float stdv = sqrtf(ss / (float)(DMODEL - 1));
    float inv = 1.0f / (stdv + 1e-6f);

#pragma unroll
    for (int c = 0; c < 3; ++c) {
        int idx = c * 256 + lane * 4;
        float4 A = *(const float4*)(ga + idx);
        float4 B = *(const float4*)(gb + idx);
        float4 o;
        o.x = A.x * (t[c].x - mean) * inv + B.x;
        o.y = A.y * (t[c].y - mean) * inv + B.y;
        o.z = A.z * (t[c].z - mean) * inv + B.z;
        o.w = A.w * (t[c].w - mean) * inv + B.w;
        *(float4*)(xr + idx) = o;
        ushort4 ob;
        ob.x = f2bf(o.x); ob.y = f2bf(o.y); ob.z = f2bf(o.z); ob.w = f2bf(o.w);
        *(ushort4*)(xbr + idx) = ob;
    }
}

// ---------------------------------------------------------------- host
struct GArg {
    const u16* A; int lda;
    const void* B; int ldb; int b_f32;
    const float* bias;
    void* C; int ldc; int c_bf16;
    u16* vt; int vt_col0; int vt_mode;
    int N, M, K; int relu;
};
template<int TM, int TN, int WR, int WC>
static inline void glaunch(hipStream_t st, const GArg& a, int splitk = 1, float* C2 = nullptr) {
    dim3 grid(a.M / TN, a.N / TM, splitk);
    hipLaunchKernelGGL((gemm_mfma<TM, TN, WR, WC>), grid, dim3(WR * WC * 64), 0, st,
                       a.A, a.lda, a.B, a.ldb, a.b_f32, a.bias, a.C, a.ldc, a.c_bf16,
                       C2, a.vt, a.vt_col0, a.vt_mode, a.K / splitk, a.relu);
}

extern "C" void kernel_launch(void* const* d_in, const int* in_sizes, int n_in,
                              void* d_out, int out_size, void* d_ws, size_t ws_size,
                              hipStream_t stream) {
    const float* xl      = (const float*)d_in[0];
    const float* dl      = (const float*)d_in[1];
    const float* pe      = (const float*)d_in[2];
    const float* enc_wq  = (const float*)d_in[3];
    const float* enc_wk  = (const float*)d_in[4];
    const float* enc_wv  = (const float*)d_in[5];
    const float* enc_wo  = (const float*)d_in[6];
    const float* enc_bo  = (const float*)d_in[7];
    const float* enc_lna = (const float*)d_in[8];
    const float* enc_lnb = (const float*)d_in[9];
    const float* enc_w1  = (const float*)d_in[10];
    const float* enc_b1  = (const float*)d_in[11];
    const float* enc_w2  = (const float*)d_in[12];
    const float* enc_b2  = (const float*)d_in[13];
    const float* dec_wq  = (const float*)d_in[14];
    const float* dec_wk  = (const float*)d_in[15];
    const float* dec_wv  = (const float*)d_in[16];
    const float* dec_wo  = (const float*)d_in[17];
    const float* dec_bo  = (const float*)d_in[18];
    const float* dec_cwq = (const float*)d_in[19];
    const float* dec_cwk = (const float*)d_in[20];
    const float* dec_cwv = (const float*)d_in[21];
    const float* dec_cwo = (const float*)d_in[22];
    const float* dec_cbo = (const float*)d_in[23];
    const float* dec_lna = (const float*)d_in[24];
    const float* dec_lnb = (const float*)d_in[25];
    const float* dec_w1  = (const float*)d_in[26];
    const float* dec_b1  = (const float*)d_in[27];
    const float* dec_w2  = (const float*)d_in[28];
    const float* dec_b2  = (const float*)d_in[29];

    const long long AC   = AC_ELEMS;
    const long long DD   = (long long)DMODEL * DMODEL;
    const long long WH   = (long long)HIDDEN * DMODEL;
    const long long QKVC = (long long)SEQ * 3 * DMODEL;
    const long long SH   = (long long)SEQ * HIDDEN;

    float* mbuf  = (float*)d_ws;
    float* xbuf  = mbuf + AC;
    float* fbuf  = xbuf + AC;
    float* fbuf2 = fbuf + AC;                  // split-K partial
    float* Opart = fbuf2 + AC;                 // [2][SEQ][DMODEL]
    float* Ml    = Opart + 2 * AC;             // [2][NHEAD][SEQ][2]
    u16* u = (u16*)(Ml + 2LL * NHEAD * SEQ * 2);
    u16* mb16 = u;  u += AC;
    u16* xb16 = u;  u += AC;
    u16* qkvb = u;  u += QKVC;      // [1024][2304]
    u16* vt   = u;  u += AC;        // self-attn V^T [768][1024]
    u16* ob   = u;  u += AC;        // attention out (combined, bf16)
    u16* hb   = u;  u += SH;        // ffn hidden
    u16* ckb  = u;  u += 12LL * AC; // cross K|V columns [1024][9216] (v cols diverted)
    u16* cvb  = u;  u += 6LL * AC;  // cross V^T [6][768][1024]

    // converted bf16 weights
    u16* W = u;
    long long woff = 0;
    const long long W_ENC_QKV = woff; woff += 18 * DD;
    const long long W_ENC_WO  = woff; woff += 6 * DD;
    const long long W_ENC_W1  = woff; woff += 6 * WH;
    const long long W_ENC_W2  = woff; woff += 6 * WH;
    const long long W_DEC_QKV = woff; woff += 18 * DD;
    const long long W_DEC_CQ  = woff; woff += 6 * DD;
    const long long W_DEC_CKV = woff; woff += 12 * DD;   // [l][k|v]
    const long long W_DEC_WO  = woff; woff += 6 * DD;
    const long long W_DEC_CWO = woff; woff += 6 * DD;
    const long long W_DEC_W1  = woff; woff += 6 * WH;
    const long long W_DEC_W2  = woff; woff += 6 * WH;
    const long long need = (long long)((char*)(W + woff) - (char*)d_ws);
    const bool conv = ((long long)ws_size >= need);

    if (conv) {
        CvtDesc dsc;
        struct Tmp { const float* src; long long dst; long long per; long long sls; long long dls; int L; };
        Tmp tmp[16] = {
            { enc_wq,  W_ENC_QKV + 0 * DD, DD, DD, 3 * DD, NLAYER },
            { enc_wk,  W_ENC_QKV + 1 * DD, DD, DD, 3 * DD, NLAYER },
            { enc_wv,  W_ENC_QKV + 2 * DD, DD, DD, 3 * DD, NLAYER },
            { enc_wo,  W_ENC_WO,  6 * DD, 0, 0, 1 },
            { enc_w1,  W_ENC_W1,  6 * WH, 0, 0, 1 },
            { enc_w2,  W_ENC_W2,  6 * WH, 0, 0, 1 },
            { dec_wq,  W_DEC_QKV + 0 * DD, DD, DD, 3 * DD, NLAYER },
            { dec_wk,  W_DEC_QKV + 1 * DD, DD, DD, 3 * DD, NLAYER },
            { dec_wv,  W_DEC_QKV + 2 * DD, DD, DD, 3 * DD, NLAYER },
            { dec_cwq, W_DEC_CQ,  6 * DD, 0, 0, 1 },
            { dec_cwk, W_DEC_CKV + 0 * DD, DD, DD, 2 * DD, NLAYER },
            { dec_cwv, W_DEC_CKV + 1 * DD, DD, DD, 2 * DD, NLAYER },
            { dec_wo,  W_DEC_WO,  6 * DD, 0, 0, 1 },
            { dec_cwo, W_DEC_CWO, 6 * DD, 0, 0, 1 },
            { dec_w1,  W_DEC_W1,  6 * WH, 0, 0, 1 },
            { dec_w2,  W_DEC_W2,  6 * WH, 0, 0, 1 },
        };
        int total = 0;
        for (int i = 0; i < 16; ++i) {
            dsc.seg[i] = { tmp[i].src, tmp[i].dst, (int)(tmp[i].per / 4096), tmp[i].sls, tmp[i].dls };
            dsc.blkStart[i] = total;
            total += (int)(tmp[i].per / 4096) * tmp[i].L;
        }
        dsc.blkStart[16] = total;
        hipLaunchKernelGGL(cvt_all, dim3(total), dim3(256), 0, stream, dsc, W);
    }

    // both stream inits in one launch (decoder stream untouched until decoder loop)
    hipLaunchKernelGGL(add_pe2, dim3((int)(AC / 256), 2), dim3(256), 0, stream,
                       xl, dl, pe, mbuf, xbuf, mb16, xb16, (int)AC);

    auto attn = [&](int causal, const u16* Qg, int ldq, const u16* Kg, int ldk, const u16* VT) {
        dim3 grid(SEQ / 64, NHEAD, 2);
        if (causal)
            hipLaunchKernelGGL((attn_split<1>), grid, dim3(256), 0, stream, Qg, ldq, Kg, ldk, VT, Opart, Ml);
        else
            hipLaunchKernelGGL((attn_split<0>), grid, dim3(256), 0, stream, Qg, ldq, Kg, ldk, VT, Opart, Ml);
        hipLaunchKernelGGL(attn_combine, dim3(SEQ), dim3(192), 0, stream, Opart, Ml, ob);
    };

    auto lnres = [&](float* x, const float* fx, const float* fx2, int n2,
                     const float* ga, const float* gb, u16* xb) {
        hipLaunchKernelGGL(ln_res_kernel, dim3(SEQ / 4), dim3(256), 0, stream,
                           x, fx, fx2, n2, ga, gb, xb);
    };

    // ---------------- encoder ----------------
    for (int l = 0; l < NLAYER; ++l) {
        if (conv) {
            GArg qkv = { mb16, DMODEL, W + W_ENC_QKV + l * 3 * DD, DMODEL, 0, nullptr,
                         qkvb, 3 * DMODEL, 1, vt, 2 * DMODEL, 1,
                         SEQ, 3 * DMODEL, DMODEL, 0 };
            glaunch<64, 64, 2, 2>(stream, qkv);
        } else {
            const float* wps[3] = { enc_wq + l * DD, enc_wk + l * DD, enc_wv + l * DD };
            for (int j = 0; j < 3; ++j) {
                GArg a = { mb16, DMODEL, wps[j], DMODEL, 1, nullptr,
                           qkvb + j * DMODEL, 3 * DMODEL, 1,
                           (j == 2) ? vt : nullptr, 0, (j == 2) ? 1 : 0,
                           SEQ, DMODEL, DMODEL, 0 };
                glaunch<32, 32, 1, 1>(stream, a);
            }
        }
        attn(0, qkvb, 3 * DMODEL, qkvb + DMODEL, 3 * DMODEL, vt);
        GArg wo = { ob, DMODEL,
                    conv ? (const void*)(W + W_ENC_WO + l * DD) : (const void*)(enc_wo + l * DD),
                    DMODEL, conv ? 0 : 1, enc_bo + (long long)l * DMODEL,
                    fbuf, DMODEL, 0, nullptr, 0, 0,
                    SEQ, DMODEL, DMODEL, 0 };
        glaunch<32, 32, 1, 1>(stream, wo);
        lnres(mbuf, fbuf, nullptr, 0,
              enc_lna + (long long)(l * 2 + 0) * DMODEL,
              enc_lnb + (long long)(l * 2 + 0) * DMODEL, mb16);
        GArg f1 = { mb16, DMODEL,
                    conv ? (const void*)(W + W_ENC_W1 + l * WH) : (const void*)(enc_w1 + l * WH),
                    DMODEL, conv ? 0 : 1, enc_b1 + (long long)l * HIDDEN,
                    hb, HIDDEN, 1, nullptr, 0, 0,
                    SEQ, HIDDEN, DMODEL, 1 };
        glaunch<64, 64, 2, 2>(stream, f1);
        GArg f2 = { hb, HIDDEN,
                    conv ? (const void*)(W + W_ENC_W2 + l * WH) : (const void*)(enc_w2 + l * WH),
                    HIDDEN, conv ? 0 : 1, enc_b2 + (long long)l * DMODEL,
                    fbuf, DMODEL, 0, nullptr, 0, 0,
                    SEQ, DMODEL, HIDDEN, 0 };
        glaunch<64, 64, 2, 2>(stream, f2, 2, fbuf2);
        lnres(mbuf, fbuf, fbuf2, 1,
              enc_lna + (long long)(l * 2 + 1) * DMODEL,
              enc_lnb + (long long)(l * 2 + 1) * DMODEL, mb16);
    }

    // batched cross K/V for ALL decoder layers (encoder output is final here)
    if (conv) {
        GArg ckv = { mb16, DMODEL, W + W_DEC_CKV, DMODEL, 0, nullptr,
                     ckb, 12 * DMODEL, 1, cvb, 0, 2,
                     SEQ, 12 * DMODEL, DMODEL, 0 };
        glaunch<64, 64, 2, 2>(stream, ckv);
    }

    // ---------------- decoder ----------------
    for (int l = 0; l < NLAYER; ++l) {
        // self attention (causal)
        if (conv) {
            GArg qkv = { xb16, DMODEL, W + W_DEC_QKV + l * 3 * DD, DMODEL, 0, nullptr,
                         qkvb, 3 * DMODEL, 1, vt, 2 * DMODEL, 1,
                         SEQ, 3 * DMODEL, DMODEL, 0 };
            glaunch<64, 64, 2, 2>(stream, qkv);
        } else {
            const float* wps[3] = { dec_wq + l * DD, dec_wk + l * DD, dec_wv + l * DD };
            for (int j = 0; j < 3; ++j) {
                GArg a = { xb16, DMODEL, wps[j], DMODEL, 1, nullptr,
                           qkvb + j * DMODEL, 3 * DMODEL, 1,
                           (j == 2) ? vt : nullptr, 0, (j == 2) ? 1 : 0,
                           SEQ, DMODEL, DMODEL, 0 };
                glaunch<32, 32, 1, 1>(stream, a);
            }
        }
        attn(1, qkvb, 3 * DMODEL, qkvb + DMODEL, 3 * DMODEL, vt);
        GArg wo = { ob, DMODEL,
                    conv ? (const void*)(W + W_DEC_WO + l * DD) : (const void*)(dec_wo + l * DD),
                    DMODEL, conv ? 0 : 1, dec_bo + (long long)l * DMODEL,
                    fbuf, DMODEL, 0, nullptr, 0, 0,
                    SEQ, DMODEL, DMODEL, 0 };
        glaunch<32, 32, 1, 1>(stream, wo);
        lnres(xbuf, fbuf, nullptr, 0,
              dec_lna + (long long)(l * 3 + 0) * DMODEL,
              dec_lnb + (long long)(l * 3 + 0) * DMODEL, xb16);

        // cross attention
        if (conv) {
            GArg q = { xb16, DMODEL, W + W_DEC_CQ + l * DD, DMODEL, 0, nullptr,
                       qkvb, 3 * DMODEL, 1, nullptr, 0, 0,
                       SEQ, DMODEL, DMODEL, 0 };
            glaunch<32, 32, 1, 1>(stream, q);
            attn(0, qkvb, 3 * DMODEL, ckb + l * 2 * DMODEL, 12 * DMODEL, cvb + (long long)l * AC);
        } else {
            GArg q = { xb16, DMODEL, dec_cwq + l * DD, DMODEL, 1, nullptr,
                       qkvb, 3 * DMODEL, 1, nullptr, 0, 0,
                       SEQ, DMODEL, DMODEL, 0 };
            glaunch<32, 32, 1, 1>(stream, q);
            GArg ck = { mb16, DMODEL, dec_cwk + l * DD, DMODEL, 1, nullptr,
                        qkvb + DMODEL, 3 * DMODEL, 1, nullptr, 0, 0,
                        SEQ, DMODEL, DMODEL, 0 };
            glaunch<32, 32, 1, 1>(stream, ck);
            GArg cv = { mb16, DMODEL, dec_cwv + l * DD, DMODEL, 1, nullptr,
                        qkvb + 2 * DMODEL, 3 * DMODEL, 1, vt, 0, 1,
                        SEQ, DMODEL, DMODEL, 0 };
            glaunch<32, 32, 1, 1>(stream, cv);
            attn(0, qkvb, 3 * DMODEL, qkvb + DMODEL, 3 * DMODEL, vt);
        }
        GArg cwo = { ob, DMODEL,
                     conv ? (const void*)(W + W_DEC_CWO + l * DD) : (const void*)(dec_cwo + l * DD),
                     DMODEL, conv ? 0 : 1, dec_cbo + (long long)l * DMODEL,
                     fbuf, DMODEL, 0, nullptr, 0, 0,
                     SEQ, DMODEL, DMODEL, 0 };
        glaunch<32, 32, 1, 1>(stream, cwo);
        lnres(xbuf, fbuf, nullptr, 0,
              dec_lna + (long long)(l * 3 + 1) * DMODEL,
              dec_lnb + (long long)(l * 3 + 1) * DMODEL, xb16);

        // FFN
        GArg f1 = { xb16, DMODEL,
                    conv ? (const void*)(W + W_DEC_W1 + l * WH) : (const void*)(dec_w1 + l * WH),
                    DMODEL, conv ? 0 : 1, dec_b1 + (long long)l * HIDDEN,
                    hb, HIDDEN, 1, nullptr, 0, 0,
                    SEQ, HIDDEN, DMODEL, 1 };
        glaunch<64, 64, 2, 2>(stream, f1);
        GArg f2 = { hb, HIDDEN,
                    conv ? (const void*)(W + W_DEC_W2 + l * WH) : (const void*)(dec_w2 + l * WH),
                    HIDDEN, conv ? 0 : 1, dec_b2 + (long long)l * DMODEL,
                    fbuf, DMODEL, 0, nullptr, 0, 0,
                    SEQ, DMODEL, HIDDEN, 0 };
        glaunch<64, 64, 2, 2>(stream, f2, 2, fbuf2);
        lnres(xbuf, fbuf, fbuf2, 1,
              dec_lna + (long long)(l * 3 + 2) * DMODEL,
              dec_lnb + (long long)(l * 3 + 2) * DMODEL, xb16);
    }

    hipLaunchKernelGGL(softmax_f32, dim3(SEQ), dim3(256), 0, stream, xbuf, (float*)d_out, DMODEL);
}